// Round 12
// baseline (60.061 us; speedup 1.0000x reference)
//
#include <hip/hip_runtime.h>
#include <math.h>

// Input: features [32, 512, 64, 64] f32. Output: 14 f32 SPP maxes (k=1,2,3).
//
// Ladder: 95.9 (atomicMax scratch) -> 57.5 (LDS bins + plain stores)
// -> [115.7 same-line atomics REV] -> [59.6 nt loads REV] -> 55.2 (1024 blk)
// -> 49.5 (compile-time bin trip counts) -> [78.7 in-kernel completion REV]
// -> 47.6 (2048 blk) -> 45.8 (4096 blk + 14-block final) -> 44.7 (8192 blk).
// Block-count gains persist past tail-exposure arithmetic (scheduling
// granularity / straggler effect). Last halving: 16384 blocks x 1 image
// (32 co-resident rounds at 2 blocks/CU; 32 x ~381 LDS-cyc ~= 5 us/CU tail
// work, overlapped under the ~42.6 us stream floor).
//
// spp_main: block b = image b (16 KiB). Thread t loads one float4 (positions
// 4t..4t+3, coalesced 16B/lane), stages to LDS sm[h*64+w]; wave q (q<14)
// reduces bin q with compile-time trip counts; one plain float store per
// (block, bin), transposed: P2[q*16384 + b]. No same-line atomics anywhere.
//
// spp_final: 14 blocks (one bin each), 256 threads, float4-coalesced scan.

#define IMG_F4 1024          // 64*64/4 float4s per image (16 KiB)
#define MAIN_BLOCKS 16384    // one block per (b, c) image
#define NBIN 14

__device__ __forceinline__ void fmax4(float4& m, const float4 v) {
    m.x = fmaxf(m.x, v.x);
    m.y = fmaxf(m.y, v.y);
    m.z = fmaxf(m.z, v.z);
    m.w = fmaxf(m.w, v.w);
}

__global__ __launch_bounds__(1024, 8)
void spp_main(const float4* __restrict__ in, float* __restrict__ P2) {
    const int t = threadIdx.x;
    const long long base = (long long)blockIdx.x * IMG_F4 + t;

    float4 m0 = in[base];    // one image per block: no fold at all

    // stage per-position values: sm[4t + e] == sm[h*64 + w]
    __shared__ float sm[4096];
    *(float4*)&sm[t * 4] = m0;
    __syncthreads();

    const int q = t >> 6;     // wave id = bin id
    const int l = t & 63;     // lane id = w coordinate
    if (q < NBIN) {
        float best = -INFINITY;
        if (q == 0) {                       // k=1: whole map, 64 rows
            float b0 = -INFINITY, b1 = -INFINITY, b2 = -INFINITY, b3 = -INFINITY;
            #pragma unroll
            for (int i = 0; i < 64; i += 4) {
                b0 = fmaxf(b0, sm[(i + 0) * 64 + l]);
                b1 = fmaxf(b1, sm[(i + 1) * 64 + l]);
                b2 = fmaxf(b2, sm[(i + 2) * 64 + l]);
                b3 = fmaxf(b3, sm[(i + 3) * 64 + l]);
            }
            best = fmaxf(fmaxf(b0, b1), fmaxf(b2, b3));
        } else if (q < 5) {                 // k=2: 32 rows, w-mask by half
            const int b = q - 1;
            const int rs = (b >> 1) * 32;
            float b0 = -INFINITY, b1 = -INFINITY, b2 = -INFINITY, b3 = -INFINITY;
            #pragma unroll
            for (int i = 0; i < 32; i += 4) {
                b0 = fmaxf(b0, sm[(rs + i + 0) * 64 + l]);
                b1 = fmaxf(b1, sm[(rs + i + 1) * 64 + l]);
                b2 = fmaxf(b2, sm[(rs + i + 2) * 64 + l]);
                b3 = fmaxf(b3, sm[(rs + i + 3) * 64 + l]);
            }
            best = fmaxf(fmaxf(b0, b1), fmaxf(b2, b3));
            if ((l >> 5) != (b & 1)) best = -INFINITY;
        } else {                            // k=3: 21 rows, col 63 + outside excluded
            const int b = q - 5;
            const int rs = (b / 3) * 21;
            float b0 = -INFINITY, b1 = -INFINITY, b2 = -INFINITY;
            #pragma unroll
            for (int i = 0; i < 21; i += 3) {
                b0 = fmaxf(b0, sm[(rs + i + 0) * 64 + l]);
                b1 = fmaxf(b1, sm[(rs + i + 1) * 64 + l]);
                b2 = fmaxf(b2, sm[(rs + i + 2) * 64 + l]);
            }
            best = fmaxf(b0, fmaxf(b1, b2));
            if (!(l < 63 && (l / 21) == (b % 3))) best = -INFINITY;
        }

        #pragma unroll
        for (int off = 32; off > 0; off >>= 1)
            best = fmaxf(best, __shfl_down(best, off, 64));

        if (l == 0) P2[q * MAIN_BLOCKS + blockIdx.x] = best;   // transposed
    }
}

// 14 blocks, one bin each: 256 threads scan P2[q*16384 .. +16384) as float4.
__global__ __launch_bounds__(256)
void spp_final(const float4* __restrict__ P2v, float* __restrict__ out) {
    const int q = blockIdx.x;
    const int t = threadIdx.x;
    const int row = q * (MAIN_BLOCKS / 4);   // 4096 float4s per bin row

    float4 m = P2v[row + t];
    #pragma unroll
    for (int j = 256; j < MAIN_BLOCKS / 4; j += 256)
        fmax4(m, P2v[row + j + t]);          // coalesced 16B/lane
    float best = fmaxf(fmaxf(m.x, m.y), fmaxf(m.z, m.w));

    #pragma unroll
    for (int off = 32; off > 0; off >>= 1)
        best = fmaxf(best, __shfl_down(best, off, 64));

    __shared__ float sw[4];
    if ((t & 63) == 0) sw[t >> 6] = best;
    __syncthreads();
    if (t == 0)
        out[q] = fmaxf(fmaxf(sw[0], sw[1]), fmaxf(sw[2], sw[3]));
}

extern "C" void kernel_launch(void* const* d_in, const int* in_sizes, int n_in,
                              void* d_out, int out_size, void* d_ws, size_t ws_size,
                              hipStream_t stream) {
    const float4* in = (const float4*)d_in[0];
    float* out = (float*)d_out;
    float* P2 = (float*)d_ws;   // 14*16384 floats = 896 KiB scratch

    spp_main<<<MAIN_BLOCKS, 1024, 0, stream>>>(in, P2);
    spp_final<<<NBIN, 256, 0, stream>>>((const float4*)P2, out);
}

// Round 13
// 44.658 us; speedup vs baseline: 1.3449x; 1.3449x over previous
//
#include <hip/hip_runtime.h>
#include <math.h>

// Input: features [32, 512, 64, 64] f32. Output: 14 f32 SPP maxes (k=1,2,3).
//
// FINAL: revert to the round-11 optimum (44.7 us = 6.0 TB/s end-to-end =
// 95.4% of the 6.29 TB/s measured float4-copy ceiling).
//
// Ladder: 95.9 (atomicMax scratch) -> 57.5 (LDS bins + plain stores)
// -> [115.7 same-line atomics REV] -> [59.6 nt loads REV] -> 55.2 (1024 blk)
// -> 49.5 (compile-time bin trip counts) -> [78.7 in-kernel completion REV]
// -> 47.6 (2048 blk) -> 45.8 (4096 blk + 14-block final) -> 44.7 (8192 blk)
// -> [60.1 @ 16384 blk REV: at 1 image/block the fixed LDS-stage+bin-reduce
// tail (~381 LDS-cyc + 2 barriers) is no longer hidden under the stream --
// tail work doubled, kernel went LDS/barrier-bound]. Block-count curve is
// bracketed: 45.8 @ 4096 / 44.7 @ 8192 / 60.1 @ 16384 -> 8192 is optimal.
//
// spp_main: 8192 blocks x 1024 threads; block b reduces images [2b, 2b+2)
// (thread t owns positions 4t..4t+3, coalesced 16B/lane plain loads, one
// fold). Per-position maxes staged in LDS (sm[h*64+w]); wave q (q<14)
// reduces bin q with compile-time trip counts; one plain float store per
// (block, bin), transposed: P2[q*8192 + b]. No same-line atomics anywhere.
//
// spp_final: 14 blocks (one bin each), 256 threads, float4-coalesced scan.

#define IMG_F4 1024          // 64*64/4 float4s per image (16 KiB)
#define IMGS_PER_BLOCK 2
#define MAIN_BLOCKS 8192     // 16384 images / 2
#define NBIN 14

__device__ __forceinline__ void fmax4(float4& m, const float4 v) {
    m.x = fmaxf(m.x, v.x);
    m.y = fmaxf(m.y, v.y);
    m.z = fmaxf(m.z, v.z);
    m.w = fmaxf(m.w, v.w);
}

__global__ __launch_bounds__(1024, 8)
void spp_main(const float4* __restrict__ in, float* __restrict__ P2) {
    const int t = threadIdx.x;
    const long long base = (long long)blockIdx.x * (IMGS_PER_BLOCK * IMG_F4) + t;

    // image-axis reduction: 2 independent loads, one fold
    float4 m0 = in[base + 0 * IMG_F4];
    float4 m1 = in[base + 1 * IMG_F4];
    fmax4(m0, m1);

    // stage per-position maxes: sm[4t + e] == sm[h*64 + w]
    __shared__ float sm[4096];
    *(float4*)&sm[t * 4] = m0;
    __syncthreads();

    const int q = t >> 6;     // wave id = bin id
    const int l = t & 63;     // lane id = w coordinate
    if (q < NBIN) {
        float best = -INFINITY;
        if (q == 0) {                       // k=1: whole map, 64 rows
            float b0 = -INFINITY, b1 = -INFINITY, b2 = -INFINITY, b3 = -INFINITY;
            #pragma unroll
            for (int i = 0; i < 64; i += 4) {
                b0 = fmaxf(b0, sm[(i + 0) * 64 + l]);
                b1 = fmaxf(b1, sm[(i + 1) * 64 + l]);
                b2 = fmaxf(b2, sm[(i + 2) * 64 + l]);
                b3 = fmaxf(b3, sm[(i + 3) * 64 + l]);
            }
            best = fmaxf(fmaxf(b0, b1), fmaxf(b2, b3));
        } else if (q < 5) {                 // k=2: 32 rows, w-mask by half
            const int b = q - 1;
            const int rs = (b >> 1) * 32;
            float b0 = -INFINITY, b1 = -INFINITY, b2 = -INFINITY, b3 = -INFINITY;
            #pragma unroll
            for (int i = 0; i < 32; i += 4) {
                b0 = fmaxf(b0, sm[(rs + i + 0) * 64 + l]);
                b1 = fmaxf(b1, sm[(rs + i + 1) * 64 + l]);
                b2 = fmaxf(b2, sm[(rs + i + 2) * 64 + l]);
                b3 = fmaxf(b3, sm[(rs + i + 3) * 64 + l]);
            }
            best = fmaxf(fmaxf(b0, b1), fmaxf(b2, b3));
            if ((l >> 5) != (b & 1)) best = -INFINITY;
        } else {                            // k=3: 21 rows, col 63 + outside excluded
            const int b = q - 5;
            const int rs = (b / 3) * 21;
            float b0 = -INFINITY, b1 = -INFINITY, b2 = -INFINITY;
            #pragma unroll
            for (int i = 0; i < 21; i += 3) {
                b0 = fmaxf(b0, sm[(rs + i + 0) * 64 + l]);
                b1 = fmaxf(b1, sm[(rs + i + 1) * 64 + l]);
                b2 = fmaxf(b2, sm[(rs + i + 2) * 64 + l]);
            }
            best = fmaxf(b0, fmaxf(b1, b2));
            if (!(l < 63 && (l / 21) == (b % 3))) best = -INFINITY;
        }

        #pragma unroll
        for (int off = 32; off > 0; off >>= 1)
            best = fmaxf(best, __shfl_down(best, off, 64));

        if (l == 0) P2[q * MAIN_BLOCKS + blockIdx.x] = best;   // transposed
    }
}

// 14 blocks, one bin each: 256 threads scan P2[q*8192 .. +8192) as float4.
__global__ __launch_bounds__(256)
void spp_final(const float4* __restrict__ P2v, float* __restrict__ out) {
    const int q = blockIdx.x;
    const int t = threadIdx.x;
    const int row = q * (MAIN_BLOCKS / 4);   // 2048 float4s per bin row

    float4 m = P2v[row + t];
    #pragma unroll
    for (int j = 256; j < MAIN_BLOCKS / 4; j += 256)
        fmax4(m, P2v[row + j + t]);          // coalesced 16B/lane
    float best = fmaxf(fmaxf(m.x, m.y), fmaxf(m.z, m.w));

    #pragma unroll
    for (int off = 32; off > 0; off >>= 1)
        best = fmaxf(best, __shfl_down(best, off, 64));

    __shared__ float sw[4];
    if ((t & 63) == 0) sw[t >> 6] = best;
    __syncthreads();
    if (t == 0)
        out[q] = fmaxf(fmaxf(sw[0], sw[1]), fmaxf(sw[2], sw[3]));
}

extern "C" void kernel_launch(void* const* d_in, const int* in_sizes, int n_in,
                              void* d_out, int out_size, void* d_ws, size_t ws_size,
                              hipStream_t stream) {
    const float4* in = (const float4*)d_in[0];
    float* out = (float*)d_out;
    float* P2 = (float*)d_ws;   // 14*8192 floats = 448 KiB scratch

    spp_main<<<MAIN_BLOCKS, 1024, 0, stream>>>(in, P2);
    spp_final<<<NBIN, 256, 0, stream>>>((const float4*)P2, out);
}